// Round 1
// baseline (2682.159 us; speedup 1.0000x reference)
//
#include <hip/hip_runtime.h>
#include <cmath>

// ---------------------------------------------------------------------------
// g_s: 4x chained conv_transpose2d(k=5,s=2,p=2,op=1) + integer quant epilogues.
// Key identity: sum_{j=0}^{s-1} floor((round(w)+j)/s) == round(w)  (Hermite),
// so split_deconv == conv_t with round(w), round(b). One conv per layer.
// ---------------------------------------------------------------------------

#define KC 16  // ci chunk staged in LDS

// Pack torch-layout weights [ci][co][5][5] -> rounded [co][ci][28] (25 taps + pad)
__global__ void pack_weights(const float* __restrict__ w, float* __restrict__ wq,
                             int Cin, int Cout, int CoutPad) {
    int idx = blockIdx.x * blockDim.x + threadIdx.x;
    int total = CoutPad * Cin * 25;
    if (idx >= total) return;
    int t = idx % 25;
    int rem = idx / 25;
    int ci = rem % Cin;
    int co = rem / Cin;
    float v = 0.0f;
    if (co < Cout) v = rintf(w[(ci * Cout + co) * 25 + t]);
    wq[((size_t)co * Cin + ci) * 28 + t] = v;
}

// One transposed-conv layer + quant epilogue.
// Each thread computes a 2x2 output quad (all four parities) for 4 consecutive
// output channels. Block = 16x16 quads = 32x32 outputs.
// Tap maps (1D): even out (oy=2qy): (dy,ky) in {(0,4),(1,2),(2,0)}  [dy: row offset-1]
//                odd  out (oy=2qy+1): (dy,ky) in {(1,3),(2,1)}
__global__ __launch_bounds__(256)
void deconv_layer(const float* __restrict__ xin, const float* __restrict__ wq,
                  const float* __restrict__ bias, const float* __restrict__ muls,
                  const float* __restrict__ relus, const int* __restrict__ dvds,
                  const int* __restrict__ bitsp,
                  int layer, int Cin, int Cout, int Hin, int Win,
                  float* __restrict__ out) {
    __shared__ float xs[KC][18][20];  // [ci][row][col], col padded 18->20

    const int tid = threadIdx.x;
    const int tx = tid & 15, ty = tid >> 4;
    const int co0 = blockIdx.x * 4;
    const int qx0 = blockIdx.y * 16, qy0 = blockIdx.z * 16;
    const int qx = qx0 + tx, qy = qy0 + ty;
    const int HW = Hin * Win;

    float acc[4][4];
    #pragma unroll
    for (int a = 0; a < 4; ++a)
        #pragma unroll
        for (int b = 0; b < 4; ++b) acc[a][b] = 0.0f;

    for (int ck = 0; ck < Cin; ck += KC) {
        __syncthreads();
        // stage x[ck..ck+KC)[qy0-1 .. qy0+16][qx0-1 .. qx0+16] with zero halo
        for (int i = tid; i < KC * 324; i += 256) {
            int cil = i / 324;
            int rem = i - cil * 324;
            int r = rem / 18;
            int c = rem - r * 18;
            int iy = qy0 - 1 + r;
            int ix = qx0 - 1 + c;
            float v = 0.0f;
            if (iy >= 0 && iy < Hin && ix >= 0 && ix < Win)
                v = xin[(size_t)(ck + cil) * HW + iy * Win + ix];
            xs[cil][r][c] = v;
        }
        __syncthreads();

        for (int cil = 0; cil < KC; ++cil) {
            float xv[3][3];
            #pragma unroll
            for (int dy = 0; dy < 3; ++dy)
                #pragma unroll
                for (int dx = 0; dx < 3; ++dx)
                    xv[dy][dx] = xs[cil][ty + dy][tx + dx];

            #pragma unroll
            for (int cs = 0; cs < 4; ++cs) {
                // block-uniform address -> scalar loads (SGPR-broadcast weights)
                const float* wr = &wq[((size_t)(co0 + cs) * Cin + (ck + cil)) * 28];
                // out(0,0): even-even, 3x3 taps
                #pragma unroll
                for (int dy = 0; dy < 3; ++dy)
                    #pragma unroll
                    for (int dx = 0; dx < 3; ++dx)
                        acc[cs][0] += xv[dy][dx] * wr[(4 - 2 * dy) * 5 + (4 - 2 * dx)];
                // out(0,1): even-odd, 3x2
                #pragma unroll
                for (int dy = 0; dy < 3; ++dy)
                    #pragma unroll
                    for (int dx = 1; dx < 3; ++dx)
                        acc[cs][1] += xv[dy][dx] * wr[(4 - 2 * dy) * 5 + (5 - 2 * dx)];
                // out(1,0): odd-even, 2x3
                #pragma unroll
                for (int dy = 1; dy < 3; ++dy)
                    #pragma unroll
                    for (int dx = 0; dx < 3; ++dx)
                        acc[cs][2] += xv[dy][dx] * wr[(5 - 2 * dy) * 5 + (4 - 2 * dx)];
                // out(1,1): odd-odd, 2x2
                #pragma unroll
                for (int dy = 1; dy < 3; ++dy)
                    #pragma unroll
                    for (int dx = 1; dx < 3; ++dx)
                        acc[cs][3] += xv[dy][dx] * wr[(5 - 2 * dy) * 5 + (5 - 2 * dx)];
            }
        }
    }

    // ------------------- quant epilogue (match reference fp32 op sequence) ----
    const int dv = dvds[layer];
    const bool qmode = (layer < 3);
    float add1, div1, clp = 0.f, scl = 0.f, add2 = 0.f, div2 = 0.f;
    if (qmode) {
        add1 = ldexpf(1.0f, dv - 10);     // 2^(dv-1-CLP_K)
        div1 = ldexpf(1.0f, dv - 9);      // 2^(dv-CLP_K)
        const float relu = relus[layer];
        const int sk = (layer == 1) ? 4 : 3;
        const float bitsv = ldexpf(1.0f, bitsp[0]) - 1.0f;  // 2^Bits - 1
        {
            #pragma clang fp contract(off)
            clp = rintf(bitsv / relu * 33554432.0f);                         // * 2^25
            scl = floorf((relu + ldexpf(1.0f, sk - 1)) / ldexpf(1.0f, sk));
        }
        add2 = ldexpf(1.0f, 24 - sk);     // 2^(15+CLP_K-sk)
        div2 = ldexpf(1.0f, 25 - sk);     // 2^(16+CLP_K-sk)
    } else {
        add1 = ldexpf(1.0f, dv - 9);
        div1 = ldexpf(1.0f, dv - 8);
    }

    const int Hout = Hin * 2, Wout = Win * 2;
    const int oy0 = 2 * qy, ox0 = 2 * qx;

    #pragma unroll
    for (int cs = 0; cs < 4; ++cs) {
        const int co = co0 + cs;
        if (co < Cout) {
            const float bq = rintf(bias[co]);
            const float m = muls[co];
            float res[4];
            {
                #pragma clang fp contract(off)
                #pragma unroll
                for (int k = 0; k < 4; ++k) {
                    float v = (acc[cs][k] + bq) * m;
                    v = floorf((v + add1) / div1);
                    if (qmode) {
                        v = fminf(fmaxf(v, 0.0f), clp);
                        v = floorf((v * scl + add2) / div2);
                    } else {
                        v = v / 255.0f;
                    }
                    res[k] = v;
                }
            }
            float* base = out + (size_t)co * Hout * Wout + (size_t)oy0 * Wout + ox0;
            *(float2*)base = make_float2(res[0], res[1]);
            *(float2*)(base + Wout) = make_float2(res[2], res[3]);
        }
    }
}

extern "C" void kernel_launch(void* const* d_in, const int* in_sizes, int n_in,
                              void* d_out, int out_size, void* d_ws, size_t ws_size,
                              hipStream_t stream) {
    const float* x  = (const float*)d_in[0];
    const float* w1 = (const float*)d_in[1];
    const float* b1 = (const float*)d_in[2];
    const float* w2 = (const float*)d_in[3];
    const float* b2 = (const float*)d_in[4];
    const float* w3 = (const float*)d_in[5];
    const float* b3 = (const float*)d_in[6];
    const float* w4 = (const float*)d_in[7];
    const float* b4 = (const float*)d_in[8];
    const float* m0 = (const float*)d_in[9];
    const float* m1 = (const float*)d_in[10];
    const float* m2 = (const float*)d_in[11];
    const float* m3 = (const float*)d_in[12];
    const float* relus = (const float*)d_in[13];
    const int* dvds = (const int*)d_in[14];
    const int* bitsp = (const int*)d_in[15];
    // d_in[16] (split) is algebraically irrelevant (Hermite identity)

    float* ws = (float*)d_ws;
    // workspace layout (floats)
    const size_t o_wq1 = 0;                              // 192*320*28
    const size_t o_wq2 = o_wq1 + (size_t)192 * 320 * 28; // 192*192*28
    const size_t o_wq3 = o_wq2 + (size_t)192 * 192 * 28;
    const size_t o_wq4 = o_wq3 + (size_t)192 * 192 * 28; // 4*192*28 (co padded 3->4)
    const size_t o_a1  = o_wq4 + (size_t)4 * 192 * 28;   // 192*96*96
    const size_t o_a2  = o_a1 + (size_t)192 * 96 * 96;   // 192*192*192
    const size_t o_a3  = o_a2 + (size_t)192 * 192 * 192; // 192*384*384

    float* wq1 = ws + o_wq1;
    float* wq2 = ws + o_wq2;
    float* wq3 = ws + o_wq3;
    float* wq4 = ws + o_wq4;
    float* a1 = ws + o_a1;
    float* a2 = ws + o_a2;
    float* a3 = ws + o_a3;

    // --- weight packing ---
    {
        int t1 = 192 * 320 * 25;
        pack_weights<<<(t1 + 255) / 256, 256, 0, stream>>>(w1, wq1, 320, 192, 192);
        int t2 = 192 * 192 * 25;
        pack_weights<<<(t2 + 255) / 256, 256, 0, stream>>>(w2, wq2, 192, 192, 192);
        pack_weights<<<(t2 + 255) / 256, 256, 0, stream>>>(w3, wq3, 192, 192, 192);
        int t4 = 4 * 192 * 25;
        pack_weights<<<(t4 + 255) / 256, 256, 0, stream>>>(w4, wq4, 192, 3, 4);
    }

    // --- layers (grid.x = co-group fastest for L2 x-tile reuse) ---
    deconv_layer<<<dim3(48, 3, 3), 256, 0, stream>>>(
        x, wq1, b1, m0, relus, dvds, bitsp, 0, 320, 192, 48, 48, a1);
    deconv_layer<<<dim3(48, 6, 6), 256, 0, stream>>>(
        a1, wq2, b2, m1, relus, dvds, bitsp, 1, 192, 192, 96, 96, a2);
    deconv_layer<<<dim3(48, 12, 12), 256, 0, stream>>>(
        a2, wq3, b3, m2, relus, dvds, bitsp, 2, 192, 192, 192, 192, a3);
    deconv_layer<<<dim3(1, 24, 24), 256, 0, stream>>>(
        a3, wq4, b4, m3, relus, dvds, bitsp, 3, 192, 3, 384, 384, (float*)d_out);
}

// Round 2
// 661.594 us; speedup vs baseline: 4.0541x; 4.0541x over previous
//
#include <hip/hip_runtime.h>
#include <cmath>

// ---------------------------------------------------------------------------
// g_s: 4x chained conv_transpose2d(k=5,s=2,p=2,op=1) + integer quant epilogue.
// Hermite: sum_j floor((round(w)+j)/split) == round(w) -> one conv per layer.
// All values are small integers: round(w) (|.|<~128), activations in [0,255].
// => exact in f16; MFMA f32_32x32x16_f16 accumulates in fp32 => bit-identical.
// Sub-pixel decomposition: out quad (2x2) per input pixel; 4 parities use 25
// taps total but only 9 distinct spatial shifts of x => load A-frag once per
// shift, fire MFMA per (parity,tap).
// ---------------------------------------------------------------------------

typedef _Float16 half8 __attribute__((ext_vector_type(8)));
typedef float floatx16 __attribute__((ext_vector_type(16)));

// tap id -> (ky,kx) in the 5x5 kernel. Taps 0-8: EE(dy,dx in 0..2);
// 9-14: EO(dx in 1..2); 15-20: OE(dy in 1..2); 21-24: OO.
__device__ __forceinline__ void tap_to_k(int t, int& ky, int& kx) {
    if (t < 9)       { int dy = t/3,  dx = t%3;                 ky = 4-2*dy; kx = 4-2*dx; }
    else if (t < 15) { int u = t-9;   int dy = u/2, dx = 1+(u&1); ky = 4-2*dy; kx = 5-2*dx; }
    else if (t < 21) { int u = t-15;  int dy = 1+u/3, dx = u%3;   ky = 5-2*dy; kx = 4-2*dx; }
    else             { int u = t-21;  int dy = 1+u/2, dx = 1+(u&1); ky = 5-2*dy; kx = 5-2*dx; }
}

// f32 NCHW -> f16 NHWC (layer-1 input)
__global__ void convert_x_hwc(const float* __restrict__ x, _Float16* __restrict__ xh,
                              int C, int HW) {
    int idx = blockIdx.x * blockDim.x + threadIdx.x;
    if (idx >= C * HW) return;
    int ci = idx % C;
    int p  = idx / C;
    xh[idx] = (_Float16)x[(size_t)ci * HW + p];
}

// torch [Cin][Cout][5][5] f32 -> B-fragment-ordered f16:
// addr = (((t*KS + q)*NT + nb)*64 + lane)*8 + j
// value = round(w[ci = q*16 + (lane>>5)*8 + j][co = nb*32 + (lane&31)][ky][kx])
__global__ void pack_w(const float* __restrict__ w, _Float16* __restrict__ wpk,
                       int Cout, int NT, int KS) {
    int idx = blockIdx.x * blockDim.x + threadIdx.x;
    int total = 25 * KS * NT * 512;
    if (idx >= total) return;
    int j    = idx & 7;
    int lane = (idx >> 3) & 63;
    int rem  = idx >> 9;
    int nb   = rem % NT; rem /= NT;
    int q    = rem % KS;
    int t    = rem / KS;
    int ci = q * 16 + ((lane >> 5) << 3) + j;
    int co = nb * 32 + (lane & 31);
    int ky, kx; tap_to_k(t, ky, kx);
    float v = 0.0f;
    if (co < Cout) v = rintf(w[(size_t)(ci * Cout + co) * 25 + ky * 5 + kx]);
    wpk[idx] = (_Float16)v;
}

// shift tables: shift s9 = dy*3+dx participates in these (tap, parity) pairs
// parity: 0=EE 1=EO 2=OE 3=OO
__constant__ const int SHIFT_NT_[9]     = {1,2,2,2,4,4,2,4,4};
__constant__ const int SHIFT_TAP_[9][4] = {
    {0,0,0,0},{1,9,0,0},{2,10,0,0},{3,15,0,0},
    {4,11,16,21},{5,12,17,22},{6,18,0,0},{7,13,19,23},{8,14,20,24}};
__constant__ const int SHIFT_PAR_[9][4] = {
    {0,0,0,0},{0,1,0,0},{0,1,0,0},{0,2,0,0},
    {0,1,2,3},{0,1,2,3},{0,2,0,0},{0,1,2,3},{0,1,2,3}};

// Block tile: 128 quads (16 wide x 8 tall) x (NW*32) co x 4 parities.
// MW x NW wave grid; each wave: R m-subtiles (32 quads each) x 32 co.
// FINAL=false: store f16 NHWC activations; FINAL=true: f32 NCHW /255 output.
template<int KC, int MW, int NW, int R, bool FINAL>
__global__ __launch_bounds__(256, 2)
void deconv_mfma(const _Float16* __restrict__ xin, const _Float16* __restrict__ wpk,
                 const float* __restrict__ bias, const float* __restrict__ muls,
                 const float* __restrict__ relus, const int* __restrict__ dvds,
                 const int* __restrict__ bitsp,
                 int layer, int Cin, int Cout, int NT, int Hq, int Wq,
                 void* __restrict__ outp) {
    constexpr int KCp = KC + 8;  // pixel stride in f16: 2*KCp%128 = 16 -> conflict-free b128
    __shared__ __align__(16) _Float16 xs[180 * KCp];  // 10 rows x 18 cols x KCp

    const int tid  = threadIdx.x;
    const int lane = tid & 63;
    const int wid  = tid >> 6;
    const int wm   = wid % MW;
    const int wn   = wid / MW;

    const int qx0 = blockIdx.y * 16;
    const int qy0 = blockIdx.z * 8;
    const int n0  = blockIdx.x * (NW * 32);
    const int nb  = blockIdx.x * NW + wn;
    const int KS  = Cin >> 4;

    floatx16 acc[R][4];
    #pragma unroll
    for (int r = 0; r < R; ++r)
        #pragma unroll
        for (int p = 0; p < 4; ++p)
            #pragma unroll
            for (int e = 0; e < 16; ++e) acc[r][p][e] = 0.0f;

    const int kfrag    = (lane >> 5) << 3;   // k sub-offset within 16-slice
    const int colA     = lane & 15;          // qx within subtile
    const int rowAbase = (lane >> 4) & 1;    // quad-row within subtile

    for (int ck = 0; ck < Cin; ck += KC) {
        __syncthreads();
        constexpr int NG = KC / 8;
        for (int i = tid; i < 180 * NG; i += 256) {
            int pix = i / NG;
            int g   = i - pix * NG;
            int rr  = pix / 18, cc = pix - rr * 18;
            int y = qy0 - 1 + rr, x = qx0 - 1 + cc;
            half8 v = {0, 0, 0, 0, 0, 0, 0, 0};
            if ((unsigned)y < (unsigned)Hq && (unsigned)x < (unsigned)Wq)
                v = *(const half8*)&xin[((size_t)y * Wq + x) * Cin + ck + g * 8];
            *(half8*)&xs[pix * KCp + g * 8] = v;
        }
        __syncthreads();

        const size_t tstr = (size_t)KS * NT * 512;
        const _Float16* wq0 = wpk + ((size_t)(ck >> 4) * NT + nb) * 512 + lane * 8;

        for (int q = 0; q < KC / 16; ++q) {
            const _Float16* wq = wq0 + (size_t)q * NT * 512;
            const int koff = q * 16 + kfrag;
            #pragma unroll
            for (int s9 = 0; s9 < 9; ++s9) {
                const int dy = s9 / 3, dx = s9 % 3;
                half8 a[R];
                #pragma unroll
                for (int r = 0; r < R; ++r) {
                    const int row = (wm * R + r) * 2 + rowAbase + dy;
                    const int col = colA + dx;
                    a[r] = *(const half8*)&xs[(row * 18 + col) * KCp + koff];
                }
                #pragma unroll
                for (int u = 0; u < 4; ++u) {
                    if (u < SHIFT_NT_[s9]) {
                        const int t = SHIFT_TAP_[s9][u];
                        const int p = SHIFT_PAR_[s9][u];
                        half8 b = *(const half8*)&wq[(size_t)t * tstr];
                        #pragma unroll
                        for (int r = 0; r < R; ++r)
                            acc[r][p] = __builtin_amdgcn_mfma_f32_32x32x16_f16(
                                a[r], b, acc[r][p], 0, 0, 0);
                    }
                }
            }
        }
    }

    // ----- quant epilogue (exact fp32 op sequence; pow2 div == mul by inv) ---
    const int dv = dvds[layer];
    const bool qmode = (layer < 3);
    float add1, inv1, clp = 0.f, scl = 0.f, add2 = 0.f, inv2 = 0.f;
    if (qmode) {
        add1 = ldexpf(1.0f, dv - 10);
        inv1 = ldexpf(1.0f, -(dv - 9));
        const float relu = relus[layer];
        const int sk = (layer == 1) ? 4 : 3;
        const float bitsv = ldexpf(1.0f, bitsp[0]) - 1.0f;
        {
            #pragma clang fp contract(off)
            clp = rintf(bitsv / relu * 33554432.0f);
            scl = floorf((relu + ldexpf(1.0f, sk - 1)) * ldexpf(1.0f, -sk));
        }
        add2 = ldexpf(1.0f, 24 - sk);
        inv2 = ldexpf(1.0f, -(25 - sk));
    } else {
        add1 = ldexpf(1.0f, dv - 9);
        inv1 = ldexpf(1.0f, -(dv - 8));
    }

    const int col = lane & 31;
    const int co = n0 + wn * 32 + col;
    const bool cok = (co < Cout);
    float bq = 0.f, mm = 0.f;
    if (cok) { bq = rintf(bias[co]); mm = muls[co]; }

    const int Wout = Wq * 2, Hout = Hq * 2;
    _Float16* acto = (_Float16*)outp;
    float* fouto = (float*)outp;

    #pragma unroll
    for (int r = 0; r < R; ++r) {
        #pragma unroll
        for (int p = 0; p < 4; ++p) {
            const int py = p >> 1, px = p & 1;
            #pragma unroll
            for (int reg = 0; reg < 16; ++reg) {
                const int mrow = (reg & 3) + 8 * (reg >> 2) + 4 * (lane >> 5);
                const int qy = qy0 + (wm * R + r) * 2 + (mrow >> 4);
                const int qx = qx0 + (mrow & 15);
                float v = acc[r][p][reg];
                {
                    #pragma clang fp contract(off)
                    v = (v + bq) * mm;
                    v = floorf((v + add1) * inv1);
                    if (qmode) {
                        v = fminf(fmaxf(v, 0.0f), clp);
                        v = floorf((v * scl + add2) * inv2);
                    } else {
                        v = v / 255.0f;
                    }
                }
                if (cok) {
                    const int oy = 2 * qy + py, ox = 2 * qx + px;
                    if (!FINAL)
                        acto[((size_t)oy * Wout + ox) * Cout + co] = (_Float16)v;
                    else
                        fouto[((size_t)co * Hout + oy) * Wout + ox] = v;
                }
            }
        }
    }
}

extern "C" void kernel_launch(void* const* d_in, const int* in_sizes, int n_in,
                              void* d_out, int out_size, void* d_ws, size_t ws_size,
                              hipStream_t stream) {
    const float* x  = (const float*)d_in[0];
    const float* w1 = (const float*)d_in[1];
    const float* b1 = (const float*)d_in[2];
    const float* w2 = (const float*)d_in[3];
    const float* b2 = (const float*)d_in[4];
    const float* w3 = (const float*)d_in[5];
    const float* b3 = (const float*)d_in[6];
    const float* w4 = (const float*)d_in[7];
    const float* b4 = (const float*)d_in[8];
    const float* m0 = (const float*)d_in[9];
    const float* m1 = (const float*)d_in[10];
    const float* m2 = (const float*)d_in[11];
    const float* m3 = (const float*)d_in[12];
    const float* relus = (const float*)d_in[13];
    const int* dvds = (const int*)d_in[14];
    const int* bitsp = (const int*)d_in[15];

    _Float16* ws16 = (_Float16*)d_ws;
    size_t o = 0;
    _Float16* wpk1 = ws16 + o; o += (size_t)25 * 20 * 6 * 512;  // 1,536,000
    _Float16* wpk2 = ws16 + o; o += (size_t)25 * 12 * 6 * 512;  //   921,600
    _Float16* wpk3 = ws16 + o; o += (size_t)25 * 12 * 6 * 512;
    _Float16* wpk4 = ws16 + o; o += (size_t)25 * 12 * 1 * 512;  //   153,600
    _Float16* xh   = ws16 + o; o += (size_t)48 * 48 * 320;
    _Float16* a1   = ws16 + o; o += (size_t)96 * 96 * 192;
    _Float16* a2   = ws16 + o; o += (size_t)192 * 192 * 192;
    _Float16* a3   = ws16 + o; o += (size_t)384 * 384 * 192;

    // input conversion + weight packing
    convert_x_hwc<<<(320 * 48 * 48 + 255) / 256, 256, 0, stream>>>(x, xh, 320, 48 * 48);
    pack_w<<<(25 * 20 * 6 * 512 + 255) / 256, 256, 0, stream>>>(w1, wpk1, 192, 6, 20);
    pack_w<<<(25 * 12 * 6 * 512 + 255) / 256, 256, 0, stream>>>(w2, wpk2, 192, 6, 12);
    pack_w<<<(25 * 12 * 6 * 512 + 255) / 256, 256, 0, stream>>>(w3, wpk3, 192, 6, 12);
    pack_w<<<(25 * 12 * 1 * 512 + 255) / 256, 256, 0, stream>>>(w4, wpk4, 3, 1, 12);

    // layer 1: 48x48x320 -> 96x96x192   grid(coTiles, Wq/16, Hq/8)
    deconv_mfma<160, 2, 2, 2, false><<<dim3(3, 3, 6), 256, 0, stream>>>(
        xh, wpk1, b1, m0, relus, dvds, bitsp, 0, 320, 192, 6, 48, 48, a1);
    // layer 2: 96x96x192 -> 192x192x192
    deconv_mfma<192, 2, 2, 2, false><<<dim3(3, 6, 12), 256, 0, stream>>>(
        a1, wpk2, b2, m1, relus, dvds, bitsp, 1, 192, 192, 6, 96, 96, a2);
    // layer 3: 192x192x192 -> 384x384x192
    deconv_mfma<192, 2, 2, 2, false><<<dim3(3, 12, 24), 256, 0, stream>>>(
        a2, wpk3, b3, m2, relus, dvds, bitsp, 2, 192, 192, 6, 192, 192, a3);
    // layer 4: 384x384x192 -> 3x768x768 (final, f32 NCHW, /255)
    deconv_mfma<192, 4, 1, 1, true><<<dim3(1, 24, 48), 256, 0, stream>>>(
        a3, wpk4, b4, m3, relus, dvds, bitsp, 3, 192, 3, 1, 384, 384, (float*)d_out);
}